// Round 1
// baseline (116.038 us; speedup 1.0000x reference)
//
#include <hip/hip_runtime.h>

#define C_TOT 64
#define Dd 48
#define Hh 128
#define Ww 128
#define DHW (Dd*Hh*Ww)
#define CSPLIT 16   // channels per block

__device__ __forceinline__ void axis_interp(float c, int dim, int& lo, int& hi,
                                            float& fr, bool& valid) {
    valid = (c >= -1.0f) && (c <= (float)dim);
    c = fminf(fmaxf(c, 0.0f), (float)(dim - 1));
    float l = floorf(c);
    lo = (int)l;
    hi = min(lo + 1, dim - 1);
    fr = c - l;
}

__global__ __launch_bounds__(256) void roialign_avg3d_kernel(
    const float* __restrict__ feats, const float* __restrict__ rois,
    float* __restrict__ out)
{
    const int dz   = blockIdx.x;   // output z: 0..6
    const int r    = blockIdx.y;   // roi
    const int cb   = blockIdx.z;   // channel quarter 0..3
    const int tid  = threadIdx.x;
    const int wave = tid >> 6;     // g = z-sample index within window, 0..3
    const int lane = tid & 63;
    const int xs   = lane & 15;    // x-sample 0..15
    const int ysub = lane >> 4;    // y-sample sub-index 0..3

    __shared__ float bins[4][8][8][CSPLIT + 1];  // [g][yb][xb][c], padded

    for (int i = tid; i < 4 * 8 * 8 * (CSPLIT + 1); i += 256)
        ((float*)bins)[i] = 0.0f;

    // --- roi params (uniform per block) ---
    const float* rr = rois + r * 7;
    const int   b  = (int)rr[0];
    const float x1 = rr[1] * 0.25f, y1 = rr[2] * 0.25f, z1 = rr[3] * 0.25f;
    const float x2 = rr[4] * 0.25f, y2 = rr[5] * 0.25f, z2 = rr[6] * 0.25f;
    const float rw = fmaxf(x2 - x1, 1.0f);
    const float rh = fmaxf(y2 - y1, 1.0f);
    const float rd = fmaxf(z2 - z1, 1.0f);
    const float bsx = rw * 0.125f, bsy = rh * 0.125f, bsz = rd * 0.125f;

    // --- x interp (fixed per lane) ---
    float xc = x1 + (float)(xs >> 1) * bsx + ((float)(xs & 1) + 0.5f) * bsx * 0.5f;
    int xlo, xhi; float fx; bool vx;
    axis_interp(xc, Ww, xlo, xhi, fx, vx);

    // --- z interp (fixed per wave) ---
    const int zs = 2 * dz + wave;           // global z-sample index 0..15
    float zc = z1 + (float)(zs >> 1) * bsz + ((float)(zs & 1) + 0.5f) * bsz * 0.5f;
    int zlo, zhi; float fz; bool vz;
    axis_interp(zc, Dd, zlo, zhi, fz, vz);

    const float* fb = feats + ((size_t)b * C_TOT + (size_t)cb * CSPLIT) * (size_t)DHW;

    __syncthreads();

    const bool writer = ((lane & 1) == 0) && ((ysub & 1) == 0);
    const int  xb = xs >> 1;

    for (int yy = 0; yy < 4; ++yy) {
        const int ys = 4 * yy + ysub;       // y-sample index 0..15
        float yc = y1 + (float)(ys >> 1) * bsy + ((float)(ys & 1) + 0.5f) * bsy * 0.5f;
        int ylo, yhi; float fy; bool vy;
        axis_interp(yc, Hh, ylo, yhi, fy, vy);
        const int yb = 2 * yy + (ysub >> 1);

        const float s  = (vx && vy && vz) ? 1.0f : 0.0f;
        const float wz0 = 1.0f - fz, wz1 = fz;
        const float wy0 = 1.0f - fy, wy1 = fy;
        const float wx0 = 1.0f - fx, wx1 = fx;
        const float w000 = s * wz0 * wy0 * wx0, w001 = s * wz0 * wy0 * wx1;
        const float w010 = s * wz0 * wy1 * wx0, w011 = s * wz0 * wy1 * wx1;
        const float w100 = s * wz1 * wy0 * wx0, w101 = s * wz1 * wy0 * wx1;
        const float w110 = s * wz1 * wy1 * wx0, w111 = s * wz1 * wy1 * wx1;

        const int o000 = (zlo * Hh + ylo) * Ww + xlo;
        const int o001 = (zlo * Hh + ylo) * Ww + xhi;
        const int o010 = (zlo * Hh + yhi) * Ww + xlo;
        const int o011 = (zlo * Hh + yhi) * Ww + xhi;
        const int o100 = (zhi * Hh + ylo) * Ww + xlo;
        const int o101 = (zhi * Hh + ylo) * Ww + xhi;
        const int o110 = (zhi * Hh + yhi) * Ww + xlo;
        const int o111 = (zhi * Hh + yhi) * Ww + xhi;

        for (int c = 0; c < CSPLIT; ++c) {
            const float* p = fb + (size_t)c * DHW;
            float v = w000 * p[o000] + w001 * p[o001]
                    + w010 * p[o010] + w011 * p[o011]
                    + w100 * p[o100] + w101 * p[o101]
                    + w110 * p[o110] + w111 * p[o111];
            // reduce 2 x-samples and 2 y-samples into the bin partial
            v += __shfl_xor(v, 1);
            v += __shfl_xor(v, 16);
            if (writer)
                bins[wave][yb][xb][c] += v;
        }
    }
    __syncthreads();

    // --- fused 2x2x2 stride-1 avg pool over bins; /64 = /8 (sr^3) / 8 (pool) ---
    for (int i = tid; i < CSPLIT * 7 * 7; i += 256) {
        const int w = i % 7;
        const int h = (i / 7) % 7;
        const int c = i / 49;
        float acc = 0.0f;
        #pragma unroll
        for (int g = 0; g < 4; ++g)
            acc += bins[g][h    ][w][c] + bins[g][h    ][w + 1][c]
                 + bins[g][h + 1][w][c] + bins[g][h + 1][w + 1][c];
        acc *= (1.0f / 64.0f);
        const int cg = cb * CSPLIT + c;
        out[((((size_t)r * C_TOT + cg) * 7 + dz) * 7 + h) * 7 + w] = acc;
    }
}

extern "C" void kernel_launch(void* const* d_in, const int* in_sizes, int n_in,
                              void* d_out, int out_size, void* d_ws, size_t ws_size,
                              hipStream_t stream) {
    const float* feats = (const float*)d_in[0];
    const float* rois  = (const float*)d_in[1];
    float* out = (float*)d_out;
    const int R = in_sizes[1] / 7;   // 64
    dim3 grid(7, R, C_TOT / CSPLIT);
    roialign_avg3d_kernel<<<grid, 256, 0, stream>>>(feats, rois, out);
}

// Round 2
// 74.529 us; speedup vs baseline: 1.5570x; 1.5570x over previous
//
#include <hip/hip_runtime.h>

#define C_TOT 64
#define Dd 48
#define Hh 128
#define Ww 128
#define DHW (Dd*Hh*Ww)
#define CSPLIT 8            // channels per block
#define CPAD  (CSPLIT + 1)  // LDS pad

__device__ __forceinline__ void axis_interp(float c, int dim, int& lo, int& hi,
                                            float& fr, bool& valid) {
    valid = (c >= -1.0f) && (c <= (float)dim);
    c = fminf(fmaxf(c, 0.0f), (float)(dim - 1));
    float l = floorf(c);
    lo = (int)l;
    hi = min(lo + 1, dim - 1);
    fr = c - l;
}

__global__ __launch_bounds__(1024) void roialign_avg3d_kernel(
    const float* __restrict__ feats, const float* __restrict__ rois,
    float* __restrict__ out)
{
    const int r    = blockIdx.x;   // roi
    const int cb   = blockIdx.y;   // channel octet 0..7
    const int tid  = threadIdx.x;
    const int wave = tid >> 6;     // z-sample index 0..15 (each wave owns one)
    const int lane = tid & 63;
    const int xs   = lane & 15;    // x-sample 0..15
    const int ysub = lane >> 4;    // y-sample sub-index 0..3

    // bins[z-sample][yb][xb][c] — each wave writes only its own z-slice
    __shared__ float bins[16][8][8][CPAD];

    for (int i = tid; i < 16 * 8 * 8 * CPAD; i += 1024)
        ((float*)bins)[i] = 0.0f;

    // --- roi params (uniform per block) ---
    const float* rr = rois + r * 7;
    const int   b  = (int)rr[0];
    const float x1 = rr[1] * 0.25f, y1 = rr[2] * 0.25f, z1 = rr[3] * 0.25f;
    const float x2 = rr[4] * 0.25f, y2 = rr[5] * 0.25f, z2 = rr[6] * 0.25f;
    const float rw = fmaxf(x2 - x1, 1.0f);
    const float rh = fmaxf(y2 - y1, 1.0f);
    const float rd = fmaxf(z2 - z1, 1.0f);
    const float bsx = rw * 0.125f, bsy = rh * 0.125f, bsz = rd * 0.125f;

    // --- x interp (fixed per lane) ---
    float xc = x1 + (float)(xs >> 1) * bsx + ((float)(xs & 1) + 0.5f) * bsx * 0.5f;
    int xlo, xhi; float fx; bool vx;
    axis_interp(xc, Ww, xlo, xhi, fx, vx);

    // --- z interp (fixed per wave) ---
    const int zs = wave;                    // global z-sample index 0..15
    float zc = z1 + (float)(zs >> 1) * bsz + ((float)(zs & 1) + 0.5f) * bsz * 0.5f;
    int zlo, zhi; float fz; bool vz;
    axis_interp(zc, Dd, zlo, zhi, fz, vz);

    const float* fb = feats + ((size_t)b * C_TOT + (size_t)cb * CSPLIT) * (size_t)DHW;

    __syncthreads();

    const bool writer = ((lane & 1) == 0) && ((ysub & 1) == 0);
    const int  xb = xs >> 1;

    for (int yy = 0; yy < 4; ++yy) {
        const int ys = 4 * yy + ysub;       // y-sample index 0..15
        float yc = y1 + (float)(ys >> 1) * bsy + ((float)(ys & 1) + 0.5f) * bsy * 0.5f;
        int ylo, yhi; float fy; bool vy;
        axis_interp(yc, Hh, ylo, yhi, fy, vy);
        const int yb = 2 * yy + (ysub >> 1);

        const float s  = (vx && vy && vz) ? 1.0f : 0.0f;
        const float wz0 = 1.0f - fz, wz1 = fz;
        const float wy0 = 1.0f - fy, wy1 = fy;
        const float wx0 = 1.0f - fx, wx1 = fx;
        const float w000 = s * wz0 * wy0 * wx0, w001 = s * wz0 * wy0 * wx1;
        const float w010 = s * wz0 * wy1 * wx0, w011 = s * wz0 * wy1 * wx1;
        const float w100 = s * wz1 * wy0 * wx0, w101 = s * wz1 * wy0 * wx1;
        const float w110 = s * wz1 * wy1 * wx0, w111 = s * wz1 * wy1 * wx1;

        const int o000 = (zlo * Hh + ylo) * Ww + xlo;
        const int o001 = (zlo * Hh + ylo) * Ww + xhi;
        const int o010 = (zlo * Hh + yhi) * Ww + xlo;
        const int o011 = (zlo * Hh + yhi) * Ww + xhi;
        const int o100 = (zhi * Hh + ylo) * Ww + xlo;
        const int o101 = (zhi * Hh + ylo) * Ww + xhi;
        const int o110 = (zhi * Hh + yhi) * Ww + xlo;
        const int o111 = (zhi * Hh + yhi) * Ww + xhi;

        #pragma unroll 2
        for (int c = 0; c < CSPLIT; ++c) {
            const float* p = fb + (size_t)c * DHW;
            float v = w000 * p[o000] + w001 * p[o001]
                    + w010 * p[o010] + w011 * p[o011]
                    + w100 * p[o100] + w101 * p[o101]
                    + w110 * p[o110] + w111 * p[o111];
            // reduce 2 x-samples and 2 y-samples into the bin partial
            v += __shfl_xor(v, 1);
            v += __shfl_xor(v, 16);
            if (writer)
                bins[zs][yb][xb][c] += v;
        }
    }
    __syncthreads();

    // --- fused pooling: out(dz,h,w) = (1/64) * sum over 4 z-slices, 2 yb, 2 xb ---
    for (int i = tid; i < CSPLIT * 7 * 7 * 7; i += 1024) {
        const int w  = i % 7;
        const int h  = (i / 7) % 7;
        const int dz = (i / 49) % 7;
        const int c  = i / 343;
        float acc = 0.0f;
        #pragma unroll
        for (int g = 0; g < 4; ++g) {
            const int z = 2 * dz + g;
            acc += bins[z][h    ][w][c] + bins[z][h    ][w + 1][c]
                 + bins[z][h + 1][w][c] + bins[z][h + 1][w + 1][c];
        }
        acc *= (1.0f / 64.0f);
        const int cg = cb * CSPLIT + c;
        out[((((size_t)r * C_TOT + cg) * 7 + dz) * 7 + h) * 7 + w] = acc;
    }
}

extern "C" void kernel_launch(void* const* d_in, const int* in_sizes, int n_in,
                              void* d_out, int out_size, void* d_ws, size_t ws_size,
                              hipStream_t stream) {
    const float* feats = (const float*)d_in[0];
    const float* rois  = (const float*)d_in[1];
    float* out = (float*)d_out;
    const int R = in_sizes[1] / 7;   // 64
    dim3 grid(R, C_TOT / CSPLIT);
    roialign_avg3d_kernel<<<grid, 1024, 0, stream>>>(feats, rois, out);
}

// Round 3
// 48.516 us; speedup vs baseline: 2.3917x; 1.5362x over previous
//
#include <hip/hip_runtime.h>

#define C_TOT 64
#define Dd 48
#define Hh 128
#define Ww 128
#define DHW (Dd*Hh*Ww)
#define CSPLIT 8            // channels per block
#define CPAD  (CSPLIT + 1)  // LDS pad

// 2-float vector with 4-byte alignment: one dwordx2 gather per x-corner-pair
typedef float f2v __attribute__((ext_vector_type(2), aligned(4)));

__device__ __forceinline__ void axis_interp(float c, int dim, int& lo, int& hi,
                                            float& fr, bool& valid) {
    valid = (c >= -1.0f) && (c <= (float)dim);
    c = fminf(fmaxf(c, 0.0f), (float)(dim - 1));
    float l = floorf(c);
    lo = (int)l;
    hi = min(lo + 1, dim - 1);
    fr = c - l;
}

__global__ __launch_bounds__(1024) void roialign_avg3d_kernel(
    const float* __restrict__ feats, const float* __restrict__ rois,
    float* __restrict__ out)
{
    const int r    = blockIdx.x;   // roi
    const int cb   = blockIdx.y;   // channel octet 0..7
    const int tid  = threadIdx.x;
    const int wave = tid >> 6;     // z-sample index 0..15 (each wave owns one)
    const int lane = tid & 63;
    const int xs   = lane & 15;    // x-sample 0..15
    const int ysub = lane >> 4;    // y-sample sub-index 0..3

    // bins[z-sample][yb][xb][c] — each wave writes only its own z-slice
    __shared__ float bins[16][8][8][CPAD];

    for (int i = tid; i < 16 * 8 * 8 * CPAD; i += 1024)
        ((float*)bins)[i] = 0.0f;

    // --- roi params (uniform per block) ---
    const float* rr = rois + r * 7;
    const int   b  = (int)rr[0];
    const float x1 = rr[1] * 0.25f, y1 = rr[2] * 0.25f, z1 = rr[3] * 0.25f;
    const float x2 = rr[4] * 0.25f, y2 = rr[5] * 0.25f, z2 = rr[6] * 0.25f;
    const float rw = fmaxf(x2 - x1, 1.0f);
    const float rh = fmaxf(y2 - y1, 1.0f);
    const float rd = fmaxf(z2 - z1, 1.0f);
    const float bsx = rw * 0.125f, bsy = rh * 0.125f, bsz = rd * 0.125f;

    // --- x interp (fixed per lane, hoisted out of all loops) ---
    float xc = x1 + (float)(xs >> 1) * bsx + ((float)(xs & 1) + 0.5f) * bsx * 0.5f;
    int xlo, xhi; float fx; bool vx;
    axis_interp(xc, Ww, xlo, xhi, fx, vx);
    const int  xb0  = min(xlo, Ww - 2);   // dwordx2 base: covers xlo and xhi
    const bool xsel = (xlo > xb0);        // true only when xlo clamped to 127 (fx==0)

    // --- z interp (fixed per wave) ---
    const int zs = wave;                    // global z-sample index 0..15
    float zc = z1 + (float)(zs >> 1) * bsz + ((float)(zs & 1) + 0.5f) * bsz * 0.5f;
    int zlo, zhi; float fz; bool vz;
    axis_interp(zc, Dd, zlo, zhi, fz, vz);

    const float* fb = feats + ((size_t)b * C_TOT + (size_t)cb * CSPLIT) * (size_t)DHW;

    __syncthreads();

    const bool writer = ((lane & 1) == 0) && ((ysub & 1) == 0);
    const int  xb = xs >> 1;

    for (int yy = 0; yy < 4; ++yy) {
        const int ys = 4 * yy + ysub;       // y-sample index 0..15
        float yc = y1 + (float)(ys >> 1) * bsy + ((float)(ys & 1) + 0.5f) * bsy * 0.5f;
        int ylo, yhi; float fy; bool vy;
        axis_interp(yc, Hh, ylo, yhi, fy, vy);
        const int yb = 2 * yy + (ysub >> 1);

        const float s  = (vx && vy && vz) ? 1.0f : 0.0f;
        const float wz0 = 1.0f - fz, wz1 = fz;
        const float wy0 = 1.0f - fy, wy1 = fy;
        // row weights (validity folded in)
        const float wa = s * wz0 * wy0, wb2 = s * wz0 * wy1;
        const float wc2 = s * wz1 * wy0, wd = s * wz1 * wy1;

        // 4 row offsets; each dwordx2 load covers both x-corners
        const int o00 = (zlo * Hh + ylo) * Ww + xb0;
        const int o01 = (zlo * Hh + yhi) * Ww + xb0;
        const int o10 = (zhi * Hh + ylo) * Ww + xb0;
        const int o11 = (zhi * Hh + yhi) * Ww + xb0;

        #pragma unroll 2
        for (int c = 0; c < CSPLIT; ++c) {
            const float* p = fb + (size_t)c * DHW;
            f2v r00 = *(const f2v*)(p + o00);
            f2v r01 = *(const f2v*)(p + o01);
            f2v r10 = *(const f2v*)(p + o10);
            f2v r11 = *(const f2v*)(p + o11);
            // x-interp per row: flo is .y only in the clamped xlo==127 case
            float f00 = xsel ? r00.y : r00.x;
            float f01 = xsel ? r01.y : r01.x;
            float f10 = xsel ? r10.y : r10.x;
            float f11 = xsel ? r11.y : r11.x;
            float x00 = f00 + fx * (r00.y - f00);
            float x01 = f01 + fx * (r01.y - f01);
            float x10 = f10 + fx * (r10.y - f10);
            float x11 = f11 + fx * (r11.y - f11);
            float v = wa * x00 + wb2 * x01 + wc2 * x10 + wd * x11;
            // reduce 2 x-samples and 2 y-samples into the bin partial
            v += __shfl_xor(v, 1);
            v += __shfl_xor(v, 16);
            if (writer)
                bins[zs][yb][xb][c] += v;
        }
    }
    __syncthreads();

    // --- fused pooling: out(dz,h,w) = (1/64) * sum over 4 z-slices, 2 yb, 2 xb ---
    for (int i = tid; i < CSPLIT * 7 * 7 * 7; i += 1024) {
        const int w  = i % 7;
        const int h  = (i / 7) % 7;
        const int dz = (i / 49) % 7;
        const int c  = i / 343;
        float acc = 0.0f;
        #pragma unroll
        for (int g = 0; g < 4; ++g) {
            const int z = 2 * dz + g;
            acc += bins[z][h    ][w][c] + bins[z][h    ][w + 1][c]
                 + bins[z][h + 1][w][c] + bins[z][h + 1][w + 1][c];
        }
        acc *= (1.0f / 64.0f);
        const int cg = cb * CSPLIT + c;
        out[((((size_t)r * C_TOT + cg) * 7 + dz) * 7 + h) * 7 + w] = acc;
    }
}

extern "C" void kernel_launch(void* const* d_in, const int* in_sizes, int n_in,
                              void* d_out, int out_size, void* d_ws, size_t ws_size,
                              hipStream_t stream) {
    const float* feats = (const float*)d_in[0];
    const float* rois  = (const float*)d_in[1];
    float* out = (float*)d_out;
    const int R = in_sizes[1] / 7;   // 64
    dim3 grid(R, C_TOT / CSPLIT);
    roialign_avg3d_kernel<<<grid, 1024, 0, stream>>>(feats, rois, out);
}

// Round 4
// 41.719 us; speedup vs baseline: 2.7814x; 1.1629x over previous
//
#include <hip/hip_runtime.h>

#define C_TOT 64
#define Dd 48
#define Hh 128
#define Ww 128
#define DHW (Dd*Hh*Ww)
#define CSPLIT 8            // channels per block
#define CPAD  (CSPLIT + 1)  // LDS pad

// 4-float vector, 4-byte aligned: one gather covers both x-samples of a bin
typedef float f4v __attribute__((ext_vector_type(4), aligned(4)));

__device__ __forceinline__ void axis_interp(float c, int dim, int& lo, int& hi,
                                            float& fr, bool& valid) {
    valid = (c >= -1.0f) && (c <= (float)dim);
    c = fminf(fmaxf(c, 0.0f), (float)(dim - 1));
    float l = floorf(c);
    lo = (int)l;
    hi = min(lo + 1, dim - 1);
    fr = c - l;
}

__global__ __launch_bounds__(1024, 8) void roialign_avg3d_kernel(
    const float* __restrict__ feats, const float* __restrict__ rois,
    float* __restrict__ out)
{
    const int r    = blockIdx.x;   // roi
    const int cb   = blockIdx.y;   // channel octet 0..7
    const int tid  = threadIdx.x;
    const int wave = tid >> 6;     // z-sample index 0..15 (each wave owns one)
    const int lane = tid & 63;
    const int xb   = lane & 7;     // x-bin 0..7 (lane handles BOTH its x-samples)
    const int ysi  = lane >> 3;    // y-sample sub-index 0..7

    // bins[z-sample][yb][xb][c] — each wave writes only its own z-slice
    __shared__ float bins[16][8][8][CPAD];

    for (int i = tid; i < 16 * 8 * 8 * CPAD; i += 1024)
        ((float*)bins)[i] = 0.0f;

    // --- roi params (uniform per block) ---
    const float* rr = rois + r * 7;
    const int   b  = (int)rr[0];
    const float x1 = rr[1] * 0.25f, y1 = rr[2] * 0.25f, z1 = rr[3] * 0.25f;
    const float x2 = rr[4] * 0.25f, y2 = rr[5] * 0.25f, z2 = rr[6] * 0.25f;
    const float rw = fmaxf(x2 - x1, 1.0f);
    const float rh = fmaxf(y2 - y1, 1.0f);
    const float rd = fmaxf(z2 - z1, 1.0f);
    const float bsx = rw * 0.125f, bsy = rh * 0.125f, bsz = rd * 0.125f;

    // --- x geometry (lane-fixed): both samples of bin xb, folded into a
    //     4-wide weight vector against the dwordx4 window at `base` ---
    float xcA = x1 + (float)xb * bsx + 0.5f * bsx * 0.5f;
    float xcB = x1 + (float)xb * bsx + 1.5f * bsx * 0.5f;
    int xloA, xhiA, xloB, xhiB; float fxA, fxB; bool vxA, vxB;
    axis_interp(xcA, Ww, xloA, xhiA, fxA, vxA);
    axis_interp(xcB, Ww, xloB, xhiB, fxB, vxB);
    const int base = min(xloA, Ww - 4);   // covers xloA..xhiB (diff <= 3) and stays in-bounds
    float w0 = 0.0f, w1 = 0.0f, w2 = 0.0f, w3 = 0.0f;
    {
        const int iA = xloA - base, hA = xhiA - base;
        const int iB = xloB - base, hB = xhiB - base;
        const float a0 = vxA ? (1.0f - fxA) : 0.0f, a1 = vxA ? fxA : 0.0f;
        const float b0 = vxB ? (1.0f - fxB) : 0.0f, b1 = vxB ? fxB : 0.0f;
        w0 += (iA == 0) ? a0 : 0.0f; w1 += (iA == 1) ? a0 : 0.0f; w2 += (iA == 2) ? a0 : 0.0f; w3 += (iA == 3) ? a0 : 0.0f;
        w0 += (hA == 0) ? a1 : 0.0f; w1 += (hA == 1) ? a1 : 0.0f; w2 += (hA == 2) ? a1 : 0.0f; w3 += (hA == 3) ? a1 : 0.0f;
        w0 += (iB == 0) ? b0 : 0.0f; w1 += (iB == 1) ? b0 : 0.0f; w2 += (iB == 2) ? b0 : 0.0f; w3 += (iB == 3) ? b0 : 0.0f;
        w0 += (hB == 0) ? b1 : 0.0f; w1 += (hB == 1) ? b1 : 0.0f; w2 += (hB == 2) ? b1 : 0.0f; w3 += (hB == 3) ? b1 : 0.0f;
    }

    // --- z interp (fixed per wave) ---
    const int zs = wave;                    // global z-sample index 0..15
    float zc = z1 + (float)(zs >> 1) * bsz + ((float)(zs & 1) + 0.5f) * bsz * 0.5f;
    int zlo, zhi; float fz; bool vz;
    axis_interp(zc, Dd, zlo, zhi, fz, vz);
    const float wz0 = 1.0f - fz, wz1 = fz;
    const int zrow0 = zlo * Hh, zrow1 = zhi * Hh;

    const float* fb = feats + ((size_t)b * C_TOT + (size_t)cb * CSPLIT) * (size_t)DHW;

    __syncthreads();

    const bool writer = ((ysi & 1) == 0);

    for (int yy = 0; yy < 2; ++yy) {
        const int ys = 8 * yy + ysi;        // y-sample index 0..15
        float yc = y1 + (float)(ys >> 1) * bsy + ((float)(ys & 1) + 0.5f) * bsy * 0.5f;
        int ylo, yhi; float fy; bool vy;
        axis_interp(yc, Hh, ylo, yhi, fy, vy);
        const int yb = ys >> 1;

        const float s  = (vy && vz) ? 1.0f : 0.0f;  // vx folded into w0..w3
        const float wy0 = 1.0f - fy, wy1 = fy;
        const float wa  = s * wz0 * wy0, wb2 = s * wz0 * wy1;
        const float wc2 = s * wz1 * wy0, wd  = s * wz1 * wy1;

        const int o00 = (zrow0 + ylo) * Ww + base;
        const int o01 = (zrow0 + yhi) * Ww + base;
        const int o10 = (zrow1 + ylo) * Ww + base;
        const int o11 = (zrow1 + yhi) * Ww + base;

        #pragma unroll 2
        for (int c = 0; c < CSPLIT; ++c) {
            const float* p = fb + (size_t)c * DHW;
            f4v r00 = *(const f4v*)(p + o00);
            f4v r01 = *(const f4v*)(p + o01);
            f4v r10 = *(const f4v*)(p + o10);
            f4v r11 = *(const f4v*)(p + o11);
            // x-pair contribution per row = dot(row, w0..w3)
            float d00 = r00.x * w0 + r00.y * w1 + r00.z * w2 + r00.w * w3;
            float d01 = r01.x * w0 + r01.y * w1 + r01.z * w2 + r01.w * w3;
            float d10 = r10.x * w0 + r10.y * w1 + r10.z * w2 + r10.w * w3;
            float d11 = r11.x * w0 + r11.y * w1 + r11.z * w2 + r11.w * w3;
            float v = wa * d00 + wb2 * d01 + wc2 * d10 + wd * d11;
            // reduce the y-sample pair (ys even/odd share a bin)
            v += __shfl_xor(v, 8);
            if (writer)
                bins[zs][yb][xb][c] += v;
        }
    }
    __syncthreads();

    // --- fused pooling: out(dz,h,w) = (1/64) * sum over 4 z-slices, 2 yb, 2 xb ---
    for (int i = tid; i < CSPLIT * 7 * 7 * 7; i += 1024) {
        const int w  = i % 7;
        const int h  = (i / 7) % 7;
        const int dz = (i / 49) % 7;
        const int c  = i / 343;
        float acc = 0.0f;
        #pragma unroll
        for (int g = 0; g < 4; ++g) {
            const int z = 2 * dz + g;
            acc += bins[z][h    ][w][c] + bins[z][h    ][w + 1][c]
                 + bins[z][h + 1][w][c] + bins[z][h + 1][w + 1][c];
        }
        acc *= (1.0f / 64.0f);
        const int cg = cb * CSPLIT + c;
        out[((((size_t)r * C_TOT + cg) * 7 + dz) * 7 + h) * 7 + w] = acc;
    }
}

extern "C" void kernel_launch(void* const* d_in, const int* in_sizes, int n_in,
                              void* d_out, int out_size, void* d_ws, size_t ws_size,
                              hipStream_t stream) {
    const float* feats = (const float*)d_in[0];
    const float* rois  = (const float*)d_in[1];
    float* out = (float*)d_out;
    const int R = in_sizes[1] / 7;   // 64
    dim3 grid(R, C_TOT / CSPLIT);
    roialign_avg3d_kernel<<<grid, 1024, 0, stream>>>(feats, rois, out);
}